// Round 9
// baseline (481.797 us; speedup 1.0000x reference)
//
#include <hip/hip_runtime.h>
#include <math.h>

typedef __attribute__((ext_vector_type(8))) short bf16x8;
typedef __attribute__((ext_vector_type(4))) float f32x4;
typedef __attribute__((ext_vector_type(4))) unsigned short us4;
typedef __attribute__((ext_vector_type(8))) unsigned short us8;

constexpr int BB = 2;
constexpr int CC = 128;
constexpr int HH = 96, WW = 96;
constexpr int PP = HH * WW;        // 9216
constexpr int NN = BB * PP;        // 18432 pixels total
constexpr int CONV_BLKS = NN / 48; // 384 (x-dim of conv grid)

__device__ __forceinline__ float bf2f(unsigned short u) {
    return __uint_as_float(((unsigned)u) << 16);
}
__device__ __forceinline__ unsigned short f2bf(float f) {
    unsigned u = __float_as_uint(f);
    unsigned r = u + 0x7fff + ((u >> 16) & 1);
    return (unsigned short)(r >> 16);
}

// ---------------------------------------------------------------------------
// Weight conversion / reordering to bf16 (one dispatch).
// ---------------------------------------------------------------------------
__global__ __launch_bounds__(256)
void k_wconv(const float* __restrict__ conv_w, const float* __restrict__ qkv_w,
             const float* __restrict__ fc_w, const float* __restrict__ w_in,
             const float* __restrict__ w_out,
             unsigned short* __restrict__ wcv, unsigned short* __restrict__ wqkv,
             unsigned short* __restrict__ wfc, unsigned short* __restrict__ wi,
             unsigned short* __restrict__ wo)
{
    int gid = blockIdx.x * 256 + threadIdx.x;
    if (gid < 589824) {
        int L = gid / 147456, r = gid % 147456;
        int o = r / 1152, k = r % 1152;
        int t = k / 128, c = k % 128;
        float v = conv_w[(((size_t)(L * 128 + o) * 128 + c) * 9) + t];
        wcv[gid] = f2bf(v);
    } else if (gid < 786432) {
        int g = gid - 589824;
        int o = (g % 49152) / 128;
        float v = qkv_w[g] * (o < 128 ? 0.25f : 1.0f);
        wqkv[g] = f2bf(v);
    } else if (gid < 851968) {
        int g = gid - 786432;
        wfc[g] = f2bf(fc_w[g]);
    } else if (gid < 860160) {
        int g = gid - 851968;
        wi[g] = f2bf(w_in[g]);
    } else if (gid < 868352) {
        int g = gid - 860160;
        wo[g] = f2bf(w_out[g]);
    }
}

// x (fp32 [b][64][9216]) -> xT (bf16 [n][64])
__global__ __launch_bounds__(256)
void k_xconv(const float* __restrict__ x, unsigned short* __restrict__ xT)
{
    int n = blockIdx.x * 256 + threadIdx.x;
    int b = n / PP, p = n - b * PP;
    unsigned short* dst = xT + (size_t)n * 64;
    #pragma unroll
    for (int cg = 0; cg < 16; ++cg) {
        us4 st;
        #pragma unroll
        for (int r = 0; r < 4; ++r)
            st[r] = f2bf(x[((size_t)(b * 64 + cg * 4 + r)) * PP + p]);
        *reinterpret_cast<us4*>(dst + cg * 4) = st;
    }
}

// ---------------------------------------------------------------------------
// Dilated conv3x3 implicit GEMM, in-block K-split + o-split x4.
// Block: 192 threads = 3 waves (tap groups). blockIdx.y = o quarter (32 ch).
// Grid: (384, 4) = 1536 blocks (6/CU, 18 waves/CU).
// LDS reduce -> single f32 y plane + per-block BN channel partials.
// ---------------------------------------------------------------------------
template<int DIL>
__global__ __launch_bounds__(192)
void k_conv(const unsigned short* __restrict__ W,
            const unsigned short* __restrict__ act,
            float* __restrict__ y,
            float* __restrict__ parts,
            const unsigned short* __restrict__ zp)
{
    int tid = threadIdx.x;
    int lane = tid & 63, wz = tid >> 6;  // wz: tap group 0..2
    int l15 = lane & 15, kg = lane >> 4;

    int n_base = blockIdx.x * 48;
    int o_base = blockIdx.y * 32;

    const unsigned short* wbase[2];
    #pragma unroll
    for (int fm = 0; fm < 2; ++fm)
        wbase[fm] = W + (size_t)(o_base + fm * 16 + l15) * 1152 + kg * 8;

    const unsigned short* bbase[3];
    int iF[3], jF[3];
    #pragma unroll
    for (int fn = 0; fn < 3; ++fn) {
        int n = n_base + fn * 16 + l15;
        bbase[fn] = act + (size_t)n * 128 + kg * 8;
        int pix = n % PP;
        iF[fn] = pix / WW;
        jF[fn] = pix % WW;
    }

    f32x4 acc[2][3];
    #pragma unroll
    for (int fm = 0; fm < 2; ++fm)
        #pragma unroll
        for (int fn = 0; fn < 3; ++fn)
            acc[fm][fn] = (f32x4){0.f, 0.f, 0.f, 0.f};

    const unsigned short* zpk = zp + kg * 8;
    int t0 = wz * 3;
    #pragma unroll
    for (int tt = 0; tt < 3; ++tt) {
        int t = t0 + tt;
        int oy = (t / 3 - 1) * DIL, ox = (t % 3 - 1) * DIL;
        int disp = (oy * WW + ox) * 128;
        const unsigned short* baddr[3];
        #pragma unroll
        for (int fn = 0; fn < 3; ++fn) {
            bool v = ((unsigned)(iF[fn] + oy) < (unsigned)HH) &&
                     ((unsigned)(jF[fn] + ox) < (unsigned)WW);
            baddr[fn] = v ? (bbase[fn] + disp) : zpk;
        }
        #pragma unroll
        for (int c0 = 0; c0 < 128; c0 += 32) {
            bf16x8 a[2], b[3];
            #pragma unroll
            for (int fm = 0; fm < 2; ++fm)
                a[fm] = *reinterpret_cast<const bf16x8*>(wbase[fm] + t * 128 + c0);
            #pragma unroll
            for (int fn = 0; fn < 3; ++fn)
                b[fn] = *reinterpret_cast<const bf16x8*>(baddr[fn] + c0);
            #pragma unroll
            for (int fm = 0; fm < 2; ++fm)
                #pragma unroll
                for (int fn = 0; fn < 3; ++fn)
                    acc[fm][fn] = __builtin_amdgcn_mfma_f32_16x16x32_bf16(
                        a[fm], b[fn], acc[fm][fn], 0, 0, 0);
        }
    }

    // LDS reduce: waves wz=1,2 deposit; wz=0 accumulates.
    __shared__ float red[2][24][64];
    if (wz) {
        #pragma unroll
        for (int fm = 0; fm < 2; ++fm)
            #pragma unroll
            for (int fn = 0; fn < 3; ++fn)
                #pragma unroll
                for (int r = 0; r < 4; ++r)
                    red[wz - 1][fm * 12 + fn * 4 + r][lane] = acc[fm][fn][r];
    }
    __syncthreads();
    if (wz == 0) {
        #pragma unroll
        for (int fm = 0; fm < 2; ++fm)
            #pragma unroll
            for (int fn = 0; fn < 3; ++fn)
                #pragma unroll
                for (int r = 0; r < 4; ++r)
                    acc[fm][fn][r] += red[0][fm * 12 + fn * 4 + r][lane] +
                                      red[1][fm * 12 + fn * 4 + r][lane];

        #pragma unroll
        for (int fm = 0; fm < 2; ++fm) {
            int o0 = o_base + fm * 16 + kg * 4;
            #pragma unroll
            for (int fn = 0; fn < 3; ++fn) {
                int n = n_base + fn * 16 + l15;
                *reinterpret_cast<f32x4*>(y + (size_t)n * 128 + o0) = acc[fm][fn];
            }
        }

        // BN partials over this block's 48 pixels (channels disjoint per blockIdx.y)
        #pragma unroll
        for (int fm = 0; fm < 2; ++fm) {
            #pragma unroll
            for (int r = 0; r < 4; ++r) {
                float s = 0.f, s2 = 0.f;
                #pragma unroll
                for (int fn = 0; fn < 3; ++fn) {
                    float v = acc[fm][fn][r];
                    s += v; s2 += v * v;
                }
                #pragma unroll
                for (int m = 1; m <= 8; m <<= 1) {
                    s  += __shfl_xor(s,  m, 64);
                    s2 += __shfl_xor(s2, m, 64);
                }
                if (l15 == 0) {
                    int c = o_base + fm * 16 + kg * 4 + r;
                    parts[(size_t)blockIdx.x * 256 + c]       = s;
                    parts[(size_t)blockIdx.x * 256 + 128 + c] = s2;
                }
            }
        }
    }
}

// ---------------------------------------------------------------------------
// MFMA GEMM for 1x1 convs. Wave tile 64(M) x 16*F(N).
// MODE 0: bf16 out (+bias); MODE 2: + residual; MODE 3: f32 scatter + bias.
// ---------------------------------------------------------------------------
template<int WM, int WN, int F, int MODE>
__global__ __launch_bounds__(WM * WN * 64)
void k_gemm(const unsigned short* __restrict__ W,
            const unsigned short* __restrict__ act,
            const float* __restrict__ bias,
            const unsigned short* __restrict__ resid,
            void* __restrict__ outp,
            int Kw, int Cin, int Cout)
{
    int tid = threadIdx.x;
    int lane = tid & 63, wv = tid >> 6;
    int wm = wv % WM, wn = wv / WM;
    int l15 = lane & 15, kg = lane >> 4;

    int n_base = blockIdx.x * (WN * 16 * F) + wn * 16 * F;
    int o_base = blockIdx.y * (WM * 64) + wm * 64;

    const unsigned short* wbase[4];
    #pragma unroll
    for (int fm = 0; fm < 4; ++fm) {
        int o = o_base + fm * 16 + l15;
        wbase[fm] = W + (size_t)o * Kw + kg * 8;
    }

    const unsigned short* bbase[F];
    #pragma unroll
    for (int fn = 0; fn < F; ++fn) {
        int n = n_base + fn * 16 + l15;
        bbase[fn] = act + (size_t)n * Cin + kg * 8;
    }

    f32x4 acc[4][F];
    #pragma unroll
    for (int fm = 0; fm < 4; ++fm)
        #pragma unroll
        for (int fn = 0; fn < F; ++fn)
            acc[fm][fn] = (f32x4){0.f, 0.f, 0.f, 0.f};

    #pragma unroll
    for (int k0 = 0; k0 < 128; k0 += 32) {
        if (k0 >= Cin) break;
        bf16x8 a[4], b[F];
        #pragma unroll
        for (int fm = 0; fm < 4; ++fm)
            a[fm] = *reinterpret_cast<const bf16x8*>(wbase[fm] + k0);
        #pragma unroll
        for (int fn = 0; fn < F; ++fn)
            b[fn] = *reinterpret_cast<const bf16x8*>(bbase[fn] + k0);
        #pragma unroll
        for (int fm = 0; fm < 4; ++fm)
            #pragma unroll
            for (int fn = 0; fn < F; ++fn)
                acc[fm][fn] = __builtin_amdgcn_mfma_f32_16x16x32_bf16(
                    a[fm], b[fn], acc[fm][fn], 0, 0, 0);
    }

    #pragma unroll
    for (int fm = 0; fm < 4; ++fm) {
        #pragma unroll
        for (int fn = 0; fn < F; ++fn) {
            f32x4 v = acc[fm][fn];
            int n = n_base + fn * 16 + l15;
            int o0 = o_base + fm * 16 + kg * 4;
            if constexpr (MODE == 0 || MODE == 2) {
                if (bias) {
                    #pragma unroll
                    for (int r = 0; r < 4; ++r) v[r] += bias[o0 + r];
                }
                if constexpr (MODE == 2) {
                    us4 rv = *reinterpret_cast<const us4*>(resid + (size_t)n * Cout + o0);
                    #pragma unroll
                    for (int r = 0; r < 4; ++r) v[r] += bf2f(rv[r]);
                }
                us4 st;
                #pragma unroll
                for (int r = 0; r < 4; ++r) st[r] = f2bf(v[r]);
                *reinterpret_cast<us4*>((unsigned short*)outp + (size_t)n * Cout + o0) = st;
            } else {
                int b_ = n / PP, p = n - b_ * PP;
                float* op = (float*)outp;
                #pragma unroll
                for (int r = 0; r < 4; ++r)
                    op[((size_t)(b_ * Cout + o0 + r)) * PP + p] = v[r] + bias[o0 + r];
            }
        }
    }
}

// ---------------------------------------------------------------------------
// Finalize BN: parallel reduce per-block partials -> scale/shift per channel.
// ---------------------------------------------------------------------------
__global__ __launch_bounds__(384)
void k_bnfin(const float* __restrict__ partials, const float* __restrict__ g,
             const float* __restrict__ b, float* __restrict__ scsh)
{
    int c = blockIdx.x;
    int t = threadIdx.x;
    float s  = partials[(size_t)t * 256 + c];
    float s2 = partials[(size_t)t * 256 + 128 + c];
    #pragma unroll
    for (int m = 32; m > 0; m >>= 1) {
        s  += __shfl_down(s,  m, 64);
        s2 += __shfl_down(s2, m, 64);
    }
    __shared__ float ls[6], ls2[6];
    int wid = t >> 6;
    if ((t & 63) == 0) { ls[wid] = s; ls2[wid] = s2; }
    __syncthreads();
    if (t == 0) {
        float S = 0.f, S2 = 0.f;
        #pragma unroll
        for (int w = 0; w < 6; ++w) { S += ls[w]; S2 += ls2[w]; }
        const float inv = 1.f / (float)NN;
        float mu = S * inv;
        float var = S2 * inv - mu * mu;
        float sc = g[c] * rsqrtf(var + 1e-5f);
        scsh[c] = sc;
        scsh[128 + c] = b[c] - mu * sc;
    }
}

// BN apply + ReLU: y f32 [n][128] -> h bf16 [n][128]
__global__ __launch_bounds__(256)
void k_bnrelu(const float* __restrict__ y, const float* __restrict__ scsh,
              unsigned short* __restrict__ h)
{
    int gid = blockIdx.x * 256 + threadIdx.x;
    int c0 = (gid * 4) & 127;
    size_t idx = (size_t)gid * 4;
    f32x4 v = *reinterpret_cast<const f32x4*>(y + idx);
    us4 st;
    #pragma unroll
    for (int r = 0; r < 4; ++r) {
        float f = fmaxf(fmaf(v[r], scsh[c0 + r], scsh[128 + c0 + r]), 0.f);
        st[r] = f2bf(f);
    }
    *reinterpret_cast<us4*>(h + idx) = st;
}

// ---------------------------------------------------------------------------
// LDS-staged local channel self-attention, one (row, head) per block.
// Stage rows i-1,i,i+1 with j-halo baked in: tile[3][98][56] (q16|k16|v16,
// pad 8), zeros at col 0/97 and off-image rows -> branch-free compute.
// 192 threads; grid (192, 8). LDS 32.9 KB -> ~5 blocks/CU.
// Unit = (col j, ng): dots[4][16] from LDS, softmax, boxsum-V weighted sum.
// ---------------------------------------------------------------------------
__global__ __launch_bounds__(192)
void k_attn2(const unsigned short* __restrict__ qkv, unsigned short* __restrict__ att)
{
    __shared__ unsigned short tile[294 * 56];   // 32928 B
    int tid = threadIdx.x;
    int br = blockIdx.x;          // 0..191  (b*96 + i)
    int head = blockIdx.y;        // 0..7
    int b = br / HH, i = br - b * HH;

    // stage: 294 tile-px * 6 us8-units = 1764
    #pragma unroll
    for (int it = 0; it < 10; ++it) {
        int idx = it * 192 + tid;
        if (idx < 1764) {
            int pp = idx / 6;
            int rem = idx - pp * 6;
            int s = rem >> 1, u8 = rem & 1;
            int rr = pp / 98, cc = pp - rr * 98;
            int ai = i + rr - 1, aj = cc - 1;
            us8 val = {0, 0, 0, 0, 0, 0, 0, 0};
            if (((unsigned)ai < (unsigned)HH) && ((unsigned)aj < (unsigned)WW)) {
                int n = b * PP + ai * WW + aj;
                val = *reinterpret_cast<const us8*>(
                    qkv + (size_t)n * 384 + s * 128 + head * 16 + u8 * 8);
            }
            *reinterpret_cast<us8*>(tile + pp * 56 + s * 16 + u8 * 8) = val;
        }
    }
    __syncthreads();

    #pragma unroll
    for (int u = 0; u < 2; ++u) {
        int unit = u * 192 + tid;   // 0..383
        int j  = unit >> 2;
        int ng = unit & 3;

        float dots[4][16];
        #pragma unroll
        for (int nn = 0; nn < 4; ++nn)
            #pragma unroll
            for (int m = 0; m < 16; ++m) dots[nn][m] = 0.f;

        // QK dots over 9 neighbors (fully unrolled, branch-free)
        #pragma unroll
        for (int rr = 0; rr < 3; ++rr) {
            #pragma unroll
            for (int dj = 0; dj < 3; ++dj) {
                const unsigned short* pb = tile + (rr * 98 + j + dj) * 56;
                us4 q4 = *reinterpret_cast<const us4*>(pb + ng * 4);
                us8 k0 = *reinterpret_cast<const us8*>(pb + 16);
                us8 k1 = *reinterpret_cast<const us8*>(pb + 24);
                float kf[16];
                #pragma unroll
                for (int e = 0; e < 8; ++e) {
                    kf[e] = bf2f(k0[e]);
                    kf[8 + e] = bf2f(k1[e]);
                }
                #pragma unroll
                for (int nn = 0; nn < 4; ++nn) {
                    float qf = bf2f(q4[nn]);
                    #pragma unroll
                    for (int m = 0; m < 16; ++m)
                        dots[nn][m] = fmaf(qf, kf[m], dots[nn][m]);
                }
            }
        }

        // box sums of V (branch-free)
        float vs[16];
        #pragma unroll
        for (int m = 0; m < 16; ++m) vs[m] = 0.f;
        #pragma unroll
        for (int rr = 0; rr < 3; ++rr) {
            #pragma unroll
            for (int dj = 0; dj < 3; ++dj) {
                const unsigned short* pb = tile + (rr * 98 + j + dj) * 56;
                us8 v0 = *reinterpret_cast<const us8*>(pb + 32);
                us8 v1 = *reinterpret_cast<const us8*>(pb + 40);
                #pragma unroll
                for (int e = 0; e < 8; ++e) {
                    vs[e] += bf2f(v0[e]);
                    vs[8 + e] += bf2f(v1[e]);
                }
            }
        }

        us4 st;
        #pragma unroll
        for (int nn = 0; nn < 4; ++nn) {
            float mx = dots[nn][0];
            #pragma unroll
            for (int m = 1; m < 16; ++m) mx = fmaxf(mx, dots[nn][m]);
            float den = 0.f, o = 0.f;
            #pragma unroll
            for (int m = 0; m < 16; ++m) {
                float e = __expf(dots[nn][m] - mx);
                den += e;
                o = fmaf(e, vs[m], o);
            }
            st[nn] = f2bf(o / den);
        }
        int n = b * PP + i * WW + j;
        *reinterpret_cast<us4*>(att + (size_t)n * CC + head * 16 + ng * 4) = st;
    }
}

// ---------------------------------------------------------------------------
extern "C" void kernel_launch(void* const* d_in, const int* in_sizes, int n_in,
                              void* d_out, int out_size, void* d_ws, size_t ws_size,
                              hipStream_t stream)
{
    const float* x      = (const float*)d_in[0];
    const float* w_in   = (const float*)d_in[1];
    const float* b_in   = (const float*)d_in[2];
    const float* conv_w = (const float*)d_in[3];
    const float* bn_g   = (const float*)d_in[5];
    const float* bn_b   = (const float*)d_in[6];
    const float* qkv_w  = (const float*)d_in[7];
    const float* fc_w   = (const float*)d_in[8];
    const float* fc_b   = (const float*)d_in[9];
    const float* w_out  = (const float*)d_in[10];
    const float* b_out  = (const float*)d_in[11];

    char* ws = (char*)d_ws;
    unsigned short* zp    = (unsigned short*)(ws);                   // 4 KB zeros
    unsigned short* wcv   = (unsigned short*)(ws + 4096);
    unsigned short* wqkv  = (unsigned short*)(ws + 1183744);
    unsigned short* wfc   = (unsigned short*)(ws + 1576960);
    unsigned short* wi    = (unsigned short*)(ws + 1708032);
    unsigned short* wo    = (unsigned short*)(ws + 1724416);
    unsigned short* xT    = (unsigned short*)(ws + 1740800);
    unsigned short* bufA  = (unsigned short*)(ws + 4100096);
    float*          ybuf  = (float*)        (ws + 8818688);
    unsigned short* hbuf  = (unsigned short*)(ws + 18255872);
    unsigned short* qkvb  = (unsigned short*)(ws + 22974464);
    unsigned short* attb  = (unsigned short*)(ws + 37130240);
    float*          parts = (float*)        (ws + 41848832);
    float*          scsh  = (float*)        (ws + 42242048);

    hipMemsetAsync(zp, 0, 4096, stream);

    k_wconv<<<3392, 256, 0, stream>>>(conv_w, qkv_w, fc_w, w_in, w_out,
                                      wcv, wqkv, wfc, wi, wo);
    k_xconv<<<NN / 256, 256, 0, stream>>>(x, xT);

    // in-proj: 64 -> 128, bias -> bufA (bf16)
    k_gemm<1, 2, 3, 0><<<dim3(192, 2), 128, 0, stream>>>(
        wi, xT, b_in, nullptr, bufA, 64, 64, 128);

    for (int L = 0; L < 4; ++L) {
        const unsigned short* wc = wcv + (size_t)L * 147456;
        switch (L) {
            case 0: k_conv<1><<<dim3(CONV_BLKS, 4), 192, 0, stream>>>(wc, bufA, ybuf, parts, zp); break;
            case 1: k_conv<2><<<dim3(CONV_BLKS, 4), 192, 0, stream>>>(wc, bufA, ybuf, parts, zp); break;
            case 2: k_conv<4><<<dim3(CONV_BLKS, 4), 192, 0, stream>>>(wc, bufA, ybuf, parts, zp); break;
            case 3: k_conv<8><<<dim3(CONV_BLKS, 4), 192, 0, stream>>>(wc, bufA, ybuf, parts, zp); break;
        }
        k_bnfin<<<128, 384, 0, stream>>>(parts, bn_g + L * 128, bn_b + L * 128, scsh);
        k_bnrelu<<<2304, 256, 0, stream>>>(ybuf, scsh, hbuf);

        // qkv: 128 -> 384 -> qkvb
        k_gemm<1, 2, 3, 0><<<dim3(192, 6), 128, 0, stream>>>(
            wqkv + (size_t)L * 49152, hbuf, nullptr, nullptr, qkvb, 128, 128, 384);

        // LDS-staged attention, one (row, head) per block -> attb
        k_attn2<<<dim3(BB * HH, 8), 192, 0, stream>>>(qkvb, attb);

        // fc: 128 -> 128 + bias + residual(hbuf) -> bufA
        k_gemm<1, 2, 3, 2><<<dim3(192, 2), 128, 0, stream>>>(
            wfc + (size_t)L * 16384, attb, fc_b + L * 128, hbuf, bufA, 128, 128, 128);
    }

    // out-proj: 128 -> 64, bias, f32 scatter to d_out
    k_gemm<1, 2, 3, 3><<<dim3(192, 1), 128, 0, stream>>>(
        wo, bufA, b_out, nullptr, (float*)d_out, 128, 128, 64);
}

// Round 10
// 474.128 us; speedup vs baseline: 1.0162x; 1.0162x over previous
//
#include <hip/hip_runtime.h>
#include <math.h>

typedef __attribute__((ext_vector_type(8))) short bf16x8;
typedef __attribute__((ext_vector_type(4))) float f32x4;
typedef __attribute__((ext_vector_type(4))) unsigned short us4;
typedef __attribute__((ext_vector_type(8))) unsigned short us8;

constexpr int BB = 2;
constexpr int CC = 128;
constexpr int HH = 96, WW = 96;
constexpr int PP = HH * WW;        // 9216
constexpr int NN = BB * PP;        // 18432 pixels total
constexpr int CONV_BLKS = NN / 48; // 384 (x-dim of conv grid)

__device__ __forceinline__ float bf2f(unsigned short u) {
    return __uint_as_float(((unsigned)u) << 16);
}
__device__ __forceinline__ unsigned short f2bf(float f) {
    unsigned u = __float_as_uint(f);
    unsigned r = u + 0x7fff + ((u >> 16) & 1);
    return (unsigned short)(r >> 16);
}

// ---------------------------------------------------------------------------
// Weight conversion / reordering to bf16 (one dispatch).
// ---------------------------------------------------------------------------
__global__ __launch_bounds__(256)
void k_wconv(const float* __restrict__ conv_w, const float* __restrict__ qkv_w,
             const float* __restrict__ fc_w, const float* __restrict__ w_in,
             const float* __restrict__ w_out,
             unsigned short* __restrict__ wcv, unsigned short* __restrict__ wqkv,
             unsigned short* __restrict__ wfc, unsigned short* __restrict__ wi,
             unsigned short* __restrict__ wo)
{
    int gid = blockIdx.x * 256 + threadIdx.x;
    if (gid < 589824) {
        int L = gid / 147456, r = gid % 147456;
        int o = r / 1152, k = r % 1152;
        int t = k / 128, c = k % 128;
        float v = conv_w[(((size_t)(L * 128 + o) * 128 + c) * 9) + t];
        wcv[gid] = f2bf(v);
    } else if (gid < 786432) {
        int g = gid - 589824;
        int o = (g % 49152) / 128;
        float v = qkv_w[g] * (o < 128 ? 0.25f : 1.0f);
        wqkv[g] = f2bf(v);
    } else if (gid < 851968) {
        int g = gid - 786432;
        wfc[g] = f2bf(fc_w[g]);
    } else if (gid < 860160) {
        int g = gid - 851968;
        wi[g] = f2bf(w_in[g]);
    } else if (gid < 868352) {
        int g = gid - 860160;
        wo[g] = f2bf(w_out[g]);
    }
}

// x (fp32 [b][64][9216]) -> xT (bf16 [n][64])
__global__ __launch_bounds__(256)
void k_xconv(const float* __restrict__ x, unsigned short* __restrict__ xT)
{
    int n = blockIdx.x * 256 + threadIdx.x;
    int b = n / PP, p = n - b * PP;
    unsigned short* dst = xT + (size_t)n * 64;
    #pragma unroll
    for (int cg = 0; cg < 16; ++cg) {
        us4 st;
        #pragma unroll
        for (int r = 0; r < 4; ++r)
            st[r] = f2bf(x[((size_t)(b * 64 + cg * 4 + r)) * PP + p]);
        *reinterpret_cast<us4*>(dst + cg * 4) = st;
    }
}

// ---------------------------------------------------------------------------
// Dilated conv3x3 implicit GEMM, in-block K-split + o-split x2 (R8 config).
// Block: 192 threads = 3 waves (tap groups). blockIdx.y = o half (64 ch).
// ---------------------------------------------------------------------------
template<int DIL>
__global__ __launch_bounds__(192)
void k_conv(const unsigned short* __restrict__ W,
            const unsigned short* __restrict__ act,
            float* __restrict__ y,
            float* __restrict__ parts,
            const unsigned short* __restrict__ zp)
{
    int tid = threadIdx.x;
    int lane = tid & 63, wz = tid >> 6;
    int l15 = lane & 15, kg = lane >> 4;

    int n_base = blockIdx.x * 48;
    int o_base = blockIdx.y * 64;

    const unsigned short* wbase[4];
    #pragma unroll
    for (int fm = 0; fm < 4; ++fm)
        wbase[fm] = W + (size_t)(o_base + fm * 16 + l15) * 1152 + kg * 8;

    const unsigned short* bbase[3];
    int iF[3], jF[3];
    #pragma unroll
    for (int fn = 0; fn < 3; ++fn) {
        int n = n_base + fn * 16 + l15;
        bbase[fn] = act + (size_t)n * 128 + kg * 8;
        int pix = n % PP;
        iF[fn] = pix / WW;
        jF[fn] = pix % WW;
    }

    f32x4 acc[4][3];
    #pragma unroll
    for (int fm = 0; fm < 4; ++fm)
        #pragma unroll
        for (int fn = 0; fn < 3; ++fn)
            acc[fm][fn] = (f32x4){0.f, 0.f, 0.f, 0.f};

    const unsigned short* zpk = zp + kg * 8;
    int t0 = wz * 3;
    #pragma unroll
    for (int tt = 0; tt < 3; ++tt) {
        int t = t0 + tt;
        int oy = (t / 3 - 1) * DIL, ox = (t % 3 - 1) * DIL;
        int disp = (oy * WW + ox) * 128;
        const unsigned short* baddr[3];
        #pragma unroll
        for (int fn = 0; fn < 3; ++fn) {
            bool v = ((unsigned)(iF[fn] + oy) < (unsigned)HH) &&
                     ((unsigned)(jF[fn] + ox) < (unsigned)WW);
            baddr[fn] = v ? (bbase[fn] + disp) : zpk;
        }
        #pragma unroll
        for (int c0 = 0; c0 < 128; c0 += 32) {
            bf16x8 a[4], b[3];
            #pragma unroll
            for (int fm = 0; fm < 4; ++fm)
                a[fm] = *reinterpret_cast<const bf16x8*>(wbase[fm] + t * 128 + c0);
            #pragma unroll
            for (int fn = 0; fn < 3; ++fn)
                b[fn] = *reinterpret_cast<const bf16x8*>(baddr[fn] + c0);
            #pragma unroll
            for (int fm = 0; fm < 4; ++fm)
                #pragma unroll
                for (int fn = 0; fn < 3; ++fn)
                    acc[fm][fn] = __builtin_amdgcn_mfma_f32_16x16x32_bf16(
                        a[fm], b[fn], acc[fm][fn], 0, 0, 0);
        }
    }

    __shared__ float red[2][48][64];
    if (wz) {
        #pragma unroll
        for (int fm = 0; fm < 4; ++fm)
            #pragma unroll
            for (int fn = 0; fn < 3; ++fn)
                #pragma unroll
                for (int r = 0; r < 4; ++r)
                    red[wz - 1][fm * 12 + fn * 4 + r][lane] = acc[fm][fn][r];
    }
    __syncthreads();
    if (wz == 0) {
        #pragma unroll
        for (int fm = 0; fm < 4; ++fm)
            #pragma unroll
            for (int fn = 0; fn < 3; ++fn)
                #pragma unroll
                for (int r = 0; r < 4; ++r)
                    acc[fm][fn][r] += red[0][fm * 12 + fn * 4 + r][lane] +
                                      red[1][fm * 12 + fn * 4 + r][lane];

        #pragma unroll
        for (int fm = 0; fm < 4; ++fm) {
            int o0 = o_base + fm * 16 + kg * 4;
            #pragma unroll
            for (int fn = 0; fn < 3; ++fn) {
                int n = n_base + fn * 16 + l15;
                *reinterpret_cast<f32x4*>(y + (size_t)n * 128 + o0) = acc[fm][fn];
            }
        }

        #pragma unroll
        for (int fm = 0; fm < 4; ++fm) {
            #pragma unroll
            for (int r = 0; r < 4; ++r) {
                float s = 0.f, s2 = 0.f;
                #pragma unroll
                for (int fn = 0; fn < 3; ++fn) {
                    float v = acc[fm][fn][r];
                    s += v; s2 += v * v;
                }
                #pragma unroll
                for (int m = 1; m <= 8; m <<= 1) {
                    s  += __shfl_xor(s,  m, 64);
                    s2 += __shfl_xor(s2, m, 64);
                }
                if (l15 == 0) {
                    int c = o_base + fm * 16 + kg * 4 + r;
                    parts[(size_t)blockIdx.x * 256 + c]       = s;
                    parts[(size_t)blockIdx.x * 256 + 128 + c] = s2;
                }
            }
        }
    }
}

// ---------------------------------------------------------------------------
// MFMA GEMM for 1x1 convs. Wave tile 64(M) x 16*F(N).
// BNIN=1: B operand read from f32 y with on-the-fly BN+ReLU (scsh), else
//         from bf16 act.
// MODE 0: bf16 out (+bias)
// MODE 2: bf16 out + bias + residual recomputed as relu(bn(y)) (f32)
// MODE 3: f32 out [b][Cout][9216] scatter + bias
// ---------------------------------------------------------------------------
template<int WM, int WN, int F, int MODE, int BNIN>
__global__ __launch_bounds__(WM * WN * 64)
void k_gemm(const unsigned short* __restrict__ W,
            const unsigned short* __restrict__ act,
            const float* __restrict__ y,
            const float* __restrict__ scsh,
            const float* __restrict__ bias,
            void* __restrict__ outp,
            int Kw, int Cin, int Cout)
{
    int tid = threadIdx.x;
    int lane = tid & 63, wv = tid >> 6;
    int wm = wv % WM, wn = wv / WM;
    int l15 = lane & 15, kg = lane >> 4;

    int n_base = blockIdx.x * (WN * 16 * F) + wn * 16 * F;
    int o_base = blockIdx.y * (WM * 64) + wm * 64;

    const unsigned short* wbase[4];
    #pragma unroll
    for (int fm = 0; fm < 4; ++fm) {
        int o = o_base + fm * 16 + l15;
        wbase[fm] = W + (size_t)o * Kw + kg * 8;
    }

    const unsigned short* bbase[F];
    const float* ybase[F];
    #pragma unroll
    for (int fn = 0; fn < F; ++fn) {
        int n = n_base + fn * 16 + l15;
        if constexpr (BNIN)
            ybase[fn] = y + (size_t)n * 128 + kg * 8;
        else
            bbase[fn] = act + (size_t)n * Cin + kg * 8;
    }

    f32x4 acc[4][F];
    #pragma unroll
    for (int fm = 0; fm < 4; ++fm)
        #pragma unroll
        for (int fn = 0; fn < F; ++fn)
            acc[fm][fn] = (f32x4){0.f, 0.f, 0.f, 0.f};

    #pragma unroll
    for (int k0 = 0; k0 < 128; k0 += 32) {
        if (k0 >= Cin) break;
        bf16x8 a[4], b[F];
        #pragma unroll
        for (int fm = 0; fm < 4; ++fm)
            a[fm] = *reinterpret_cast<const bf16x8*>(wbase[fm] + k0);
        if constexpr (BNIN) {
            f32x4 sc0 = *reinterpret_cast<const f32x4*>(scsh + k0 + kg * 8);
            f32x4 sc1 = *reinterpret_cast<const f32x4*>(scsh + k0 + kg * 8 + 4);
            f32x4 sh0 = *reinterpret_cast<const f32x4*>(scsh + 128 + k0 + kg * 8);
            f32x4 sh1 = *reinterpret_cast<const f32x4*>(scsh + 128 + k0 + kg * 8 + 4);
            #pragma unroll
            for (int fn = 0; fn < F; ++fn) {
                f32x4 u0 = *reinterpret_cast<const f32x4*>(ybase[fn] + k0);
                f32x4 u1 = *reinterpret_cast<const f32x4*>(ybase[fn] + k0 + 4);
                bf16x8 bb;
                #pragma unroll
                for (int e = 0; e < 4; ++e) {
                    bb[e]     = (short)f2bf(fmaxf(fmaf(u0[e], sc0[e], sh0[e]), 0.f));
                    bb[4 + e] = (short)f2bf(fmaxf(fmaf(u1[e], sc1[e], sh1[e]), 0.f));
                }
                b[fn] = bb;
            }
        } else {
            #pragma unroll
            for (int fn = 0; fn < F; ++fn)
                b[fn] = *reinterpret_cast<const bf16x8*>(bbase[fn] + k0);
        }
        #pragma unroll
        for (int fm = 0; fm < 4; ++fm)
            #pragma unroll
            for (int fn = 0; fn < F; ++fn)
                acc[fm][fn] = __builtin_amdgcn_mfma_f32_16x16x32_bf16(
                    a[fm], b[fn], acc[fm][fn], 0, 0, 0);
    }

    #pragma unroll
    for (int fm = 0; fm < 4; ++fm) {
        #pragma unroll
        for (int fn = 0; fn < F; ++fn) {
            f32x4 v = acc[fm][fn];
            int n = n_base + fn * 16 + l15;
            int o0 = o_base + fm * 16 + kg * 4;
            if constexpr (MODE == 0 || MODE == 2) {
                if (bias) {
                    #pragma unroll
                    for (int r = 0; r < 4; ++r) v[r] += bias[o0 + r];
                }
                if constexpr (MODE == 2) {
                    // residual = relu(bn(y)) recomputed in f32
                    f32x4 yv = *reinterpret_cast<const f32x4*>(y + (size_t)n * 128 + o0);
                    #pragma unroll
                    for (int r = 0; r < 4; ++r)
                        v[r] += fmaxf(fmaf(yv[r], scsh[o0 + r], scsh[128 + o0 + r]), 0.f);
                }
                us4 st;
                #pragma unroll
                for (int r = 0; r < 4; ++r) st[r] = f2bf(v[r]);
                *reinterpret_cast<us4*>((unsigned short*)outp + (size_t)n * Cout + o0) = st;
            } else {
                int b_ = n / PP, p = n - b_ * PP;
                float* op = (float*)outp;
                #pragma unroll
                for (int r = 0; r < 4; ++r)
                    op[((size_t)(b_ * Cout + o0 + r)) * PP + p] = v[r] + bias[o0 + r];
            }
        }
    }
}

// ---------------------------------------------------------------------------
// Finalize BN: parallel reduce per-block partials -> scale/shift per channel.
// ---------------------------------------------------------------------------
__global__ __launch_bounds__(384)
void k_bnfin(const float* __restrict__ partials, const float* __restrict__ g,
             const float* __restrict__ b, float* __restrict__ scsh)
{
    int c = blockIdx.x;
    int t = threadIdx.x;
    float s  = partials[(size_t)t * 256 + c];
    float s2 = partials[(size_t)t * 256 + 128 + c];
    #pragma unroll
    for (int m = 32; m > 0; m >>= 1) {
        s  += __shfl_down(s,  m, 64);
        s2 += __shfl_down(s2, m, 64);
    }
    __shared__ float ls[6], ls2[6];
    int wid = t >> 6;
    if ((t & 63) == 0) { ls[wid] = s; ls2[wid] = s2; }
    __syncthreads();
    if (t == 0) {
        float S = 0.f, S2 = 0.f;
        #pragma unroll
        for (int w = 0; w < 6; ++w) { S += ls[w]; S2 += ls2[w]; }
        const float inv = 1.f / (float)NN;
        float mu = S * inv;
        float var = S2 * inv - mu * mu;
        float sc = g[c] * rsqrtf(var + 1e-5f);
        scsh[c] = sc;
        scsh[128 + c] = b[c] - mu * sc;
    }
}

// ---------------------------------------------------------------------------
// LDS-staged local channel self-attention, one (row, head) per block.
// tile[3][98][56] with halo baked in; branch-free compute.
// ---------------------------------------------------------------------------
__global__ __launch_bounds__(192)
void k_attn2(const unsigned short* __restrict__ qkv, unsigned short* __restrict__ att)
{
    __shared__ unsigned short tile[294 * 56];   // 32928 B
    int tid = threadIdx.x;
    int br = blockIdx.x;          // 0..191  (b*96 + i)
    int head = blockIdx.y;        // 0..7
    int b = br / HH, i = br - b * HH;

    #pragma unroll
    for (int it = 0; it < 10; ++it) {
        int idx = it * 192 + tid;
        if (idx < 1764) {
            int pp = idx / 6;
            int rem = idx - pp * 6;
            int s = rem >> 1, u8 = rem & 1;
            int rr = pp / 98, cc = pp - rr * 98;
            int ai = i + rr - 1, aj = cc - 1;
            us8 val = {0, 0, 0, 0, 0, 0, 0, 0};
            if (((unsigned)ai < (unsigned)HH) && ((unsigned)aj < (unsigned)WW)) {
                int n = b * PP + ai * WW + aj;
                val = *reinterpret_cast<const us8*>(
                    qkv + (size_t)n * 384 + s * 128 + head * 16 + u8 * 8);
            }
            *reinterpret_cast<us8*>(tile + pp * 56 + s * 16 + u8 * 8) = val;
        }
    }
    __syncthreads();

    #pragma unroll
    for (int u = 0; u < 2; ++u) {
        int unit = u * 192 + tid;   // 0..383
        int j  = unit >> 2;
        int ng = unit & 3;

        float dots[4][16];
        #pragma unroll
        for (int nn = 0; nn < 4; ++nn)
            #pragma unroll
            for (int m = 0; m < 16; ++m) dots[nn][m] = 0.f;

        #pragma unroll
        for (int rr = 0; rr < 3; ++rr) {
            #pragma unroll
            for (int dj = 0; dj < 3; ++dj) {
                const unsigned short* pb = tile + (rr * 98 + j + dj) * 56;
                us4 q4 = *reinterpret_cast<const us4*>(pb + ng * 4);
                us8 k0 = *reinterpret_cast<const us8*>(pb + 16);
                us8 k1 = *reinterpret_cast<const us8*>(pb + 24);
                float kf[16];
                #pragma unroll
                for (int e = 0; e < 8; ++e) {
                    kf[e] = bf2f(k0[e]);
                    kf[8 + e] = bf2f(k1[e]);
                }
                #pragma unroll
                for (int nn = 0; nn < 4; ++nn) {
                    float qf = bf2f(q4[nn]);
                    #pragma unroll
                    for (int m = 0; m < 16; ++m)
                        dots[nn][m] = fmaf(qf, kf[m], dots[nn][m]);
                }
            }
        }

        float vs[16];
        #pragma unroll
        for (int m = 0; m < 16; ++m) vs[m] = 0.f;
        #pragma unroll
        for (int rr = 0; rr < 3; ++rr) {
            #pragma unroll
            for (int dj = 0; dj < 3; ++dj) {
                const unsigned short* pb = tile + (rr * 98 + j + dj) * 56;
                us8 v0 = *reinterpret_cast<const us8*>(pb + 32);
                us8 v1 = *reinterpret_cast<const us8*>(pb + 40);
                #pragma unroll
                for (int e = 0; e < 8; ++e) {
                    vs[e] += bf2f(v0[e]);
                    vs[8 + e] += bf2f(v1[e]);
                }
            }
        }

        us4 st;
        #pragma unroll
        for (int nn = 0; nn < 4; ++nn) {
            float mx = dots[nn][0];
            #pragma unroll
            for (int m = 1; m < 16; ++m) mx = fmaxf(mx, dots[nn][m]);
            float den = 0.f, o = 0.f;
            #pragma unroll
            for (int m = 0; m < 16; ++m) {
                float e = __expf(dots[nn][m] - mx);
                den += e;
                o = fmaf(e, vs[m], o);
            }
            st[nn] = f2bf(o / den);
        }
        int n = b * PP + i * WW + j;
        *reinterpret_cast<us4*>(att + (size_t)n * CC + head * 16 + ng * 4) = st;
    }
}

// ---------------------------------------------------------------------------
extern "C" void kernel_launch(void* const* d_in, const int* in_sizes, int n_in,
                              void* d_out, int out_size, void* d_ws, size_t ws_size,
                              hipStream_t stream)
{
    const float* x      = (const float*)d_in[0];
    const float* w_in   = (const float*)d_in[1];
    const float* b_in   = (const float*)d_in[2];
    const float* conv_w = (const float*)d_in[3];
    const float* bn_g   = (const float*)d_in[5];
    const float* bn_b   = (const float*)d_in[6];
    const float* qkv_w  = (const float*)d_in[7];
    const float* fc_w   = (const float*)d_in[8];
    const float* fc_b   = (const float*)d_in[9];
    const float* w_out  = (const float*)d_in[10];
    const float* b_out  = (const float*)d_in[11];

    char* ws = (char*)d_ws;
    unsigned short* zp    = (unsigned short*)(ws);                   // 4 KB zeros
    unsigned short* wcv   = (unsigned short*)(ws + 4096);
    unsigned short* wqkv  = (unsigned short*)(ws + 1183744);
    unsigned short* wfc   = (unsigned short*)(ws + 1576960);
    unsigned short* wi    = (unsigned short*)(ws + 1708032);
    unsigned short* wo    = (unsigned short*)(ws + 1724416);
    unsigned short* xT    = (unsigned short*)(ws + 1740800);
    unsigned short* bufA  = (unsigned short*)(ws + 4100096);
    float*          ybuf  = (float*)        (ws + 8818688);
    unsigned short* qkvb  = (unsigned short*)(ws + 22974464);
    unsigned short* attb  = (unsigned short*)(ws + 37130240);
    float*          parts = (float*)        (ws + 41848832);
    float*          scsh  = (float*)        (ws + 42242048);

    hipMemsetAsync(zp, 0, 4096, stream);

    k_wconv<<<3392, 256, 0, stream>>>(conv_w, qkv_w, fc_w, w_in, w_out,
                                      wcv, wqkv, wfc, wi, wo);
    k_xconv<<<NN / 256, 256, 0, stream>>>(x, xT);

    // in-proj: 64 -> 128, bias -> bufA (bf16)
    k_gemm<1, 2, 3, 0, 0><<<dim3(192, 2), 128, 0, stream>>>(
        wi, xT, nullptr, nullptr, b_in, bufA, 64, 64, 128);

    for (int L = 0; L < 4; ++L) {
        const unsigned short* wc = wcv + (size_t)L * 147456;
        switch (L) {
            case 0: k_conv<1><<<dim3(CONV_BLKS, 2), 192, 0, stream>>>(wc, bufA, ybuf, parts, zp); break;
            case 1: k_conv<2><<<dim3(CONV_BLKS, 2), 192, 0, stream>>>(wc, bufA, ybuf, parts, zp); break;
            case 2: k_conv<4><<<dim3(CONV_BLKS, 2), 192, 0, stream>>>(wc, bufA, ybuf, parts, zp); break;
            case 3: k_conv<8><<<dim3(CONV_BLKS, 2), 192, 0, stream>>>(wc, bufA, ybuf, parts, zp); break;
        }
        k_bnfin<<<128, 384, 0, stream>>>(parts, bn_g + L * 128, bn_b + L * 128, scsh);

        // qkv: BN+ReLU fused on B-operand (reads ybuf f32) -> qkvb
        k_gemm<1, 2, 3, 0, 1><<<dim3(192, 6), 128, 0, stream>>>(
            wqkv + (size_t)L * 49152, nullptr, ybuf, scsh, nullptr, qkvb, 128, 128, 384);

        // LDS-staged attention -> attb
        k_attn2<<<dim3(BB * HH, 8), 192, 0, stream>>>(qkvb, attb);

        // fc: 128 -> 128 + bias + residual relu(bn(y)) -> bufA
        k_gemm<1, 2, 3, 2, 0><<<dim3(192, 2), 128, 0, stream>>>(
            wfc + (size_t)L * 16384, attb, ybuf, scsh, fc_b + L * 128, bufA, 128, 128, 128);
    }

    // out-proj: 128 -> 64, bias, f32 scatter to d_out
    k_gemm<1, 2, 3, 3, 0><<<dim3(192, 1), 128, 0, stream>>>(
        wo, bufA, nullptr, nullptr, b_out, (float*)d_out, 128, 128, 64);
}

// Round 11
// 456.573 us; speedup vs baseline: 1.0552x; 1.0384x over previous
//
#include <hip/hip_runtime.h>
#include <math.h>

typedef __attribute__((ext_vector_type(8))) short bf16x8;
typedef __attribute__((ext_vector_type(4))) float f32x4;
typedef __attribute__((ext_vector_type(4))) unsigned short us4;
typedef __attribute__((ext_vector_type(8))) unsigned short us8;

constexpr int BB = 2;
constexpr int CC = 128;
constexpr int HH = 96, WW = 96;
constexpr int PP = HH * WW;        // 9216
constexpr int NN = BB * PP;        // 18432 pixels total
constexpr int CONV_BLKS = NN / 48; // 384 (x-dim of conv grid)

__device__ __forceinline__ float bf2f(unsigned short u) {
    return __uint_as_float(((unsigned)u) << 16);
}
__device__ __forceinline__ unsigned short f2bf(float f) {
    unsigned u = __float_as_uint(f);
    unsigned r = u + 0x7fff + ((u >> 16) & 1);
    return (unsigned short)(r >> 16);
}

// ---------------------------------------------------------------------------
// Weight conversion / reordering to bf16 + x -> xT transpose (one dispatch).
// ---------------------------------------------------------------------------
__global__ __launch_bounds__(256)
void k_wconv(const float* __restrict__ conv_w, const float* __restrict__ qkv_w,
             const float* __restrict__ fc_w, const float* __restrict__ w_in,
             const float* __restrict__ w_out, const float* __restrict__ x,
             unsigned short* __restrict__ wcv, unsigned short* __restrict__ wqkv,
             unsigned short* __restrict__ wfc, unsigned short* __restrict__ wi,
             unsigned short* __restrict__ wo, unsigned short* __restrict__ xT)
{
    int gid = blockIdx.x * 256 + threadIdx.x;
    if (gid < 589824) {
        int L = gid / 147456, r = gid % 147456;
        int o = r / 1152, k = r % 1152;
        int t = k / 128, c = k % 128;
        float v = conv_w[(((size_t)(L * 128 + o) * 128 + c) * 9) + t];
        wcv[gid] = f2bf(v);
    } else if (gid < 786432) {
        int g = gid - 589824;
        int o = (g % 49152) / 128;
        float v = qkv_w[g] * (o < 128 ? 0.25f : 1.0f);
        wqkv[g] = f2bf(v);
    } else if (gid < 851968) {
        int g = gid - 786432;
        wfc[g] = f2bf(fc_w[g]);
    } else if (gid < 860160) {
        int g = gid - 851968;
        wi[g] = f2bf(w_in[g]);
    } else if (gid < 868352) {
        int g = gid - 860160;
        wo[g] = f2bf(w_out[g]);
    } else if (gid < 886784) {
        int n = gid - 868352;          // 0..18431: x transpose
        int b = n / PP, p = n - b * PP;
        unsigned short* dst = xT + (size_t)n * 64;
        #pragma unroll
        for (int cg = 0; cg < 16; ++cg) {
            us4 st;
            #pragma unroll
            for (int r = 0; r < 4; ++r)
                st[r] = f2bf(x[((size_t)(b * 64 + cg * 4 + r)) * PP + p]);
            *reinterpret_cast<us4*>(dst + cg * 4) = st;
        }
    }
}

// ---------------------------------------------------------------------------
// Dilated conv3x3 implicit GEMM, in-block K-split + o-split x2 (R8 config).
// Block: 192 threads = 3 waves (tap groups). blockIdx.y = o half (64 ch).
// BN channel partials accumulated by atomics into 16 slots (parts16L).
// ---------------------------------------------------------------------------
template<int DIL>
__global__ __launch_bounds__(192)
void k_conv(const unsigned short* __restrict__ W,
            const unsigned short* __restrict__ act,
            float* __restrict__ y,
            float* __restrict__ parts16L,
            const unsigned short* __restrict__ zp)
{
    int tid = threadIdx.x;
    int lane = tid & 63, wz = tid >> 6;
    int l15 = lane & 15, kg = lane >> 4;

    int n_base = blockIdx.x * 48;
    int o_base = blockIdx.y * 64;

    const unsigned short* wbase[4];
    #pragma unroll
    for (int fm = 0; fm < 4; ++fm)
        wbase[fm] = W + (size_t)(o_base + fm * 16 + l15) * 1152 + kg * 8;

    const unsigned short* bbase[3];
    int iF[3], jF[3];
    #pragma unroll
    for (int fn = 0; fn < 3; ++fn) {
        int n = n_base + fn * 16 + l15;
        bbase[fn] = act + (size_t)n * 128 + kg * 8;
        int pix = n % PP;
        iF[fn] = pix / WW;
        jF[fn] = pix % WW;
    }

    f32x4 acc[4][3];
    #pragma unroll
    for (int fm = 0; fm < 4; ++fm)
        #pragma unroll
        for (int fn = 0; fn < 3; ++fn)
            acc[fm][fn] = (f32x4){0.f, 0.f, 0.f, 0.f};

    const unsigned short* zpk = zp + kg * 8;
    int t0 = wz * 3;
    #pragma unroll
    for (int tt = 0; tt < 3; ++tt) {
        int t = t0 + tt;
        int oy = (t / 3 - 1) * DIL, ox = (t % 3 - 1) * DIL;
        int disp = (oy * WW + ox) * 128;
        const unsigned short* baddr[3];
        #pragma unroll
        for (int fn = 0; fn < 3; ++fn) {
            bool v = ((unsigned)(iF[fn] + oy) < (unsigned)HH) &&
                     ((unsigned)(jF[fn] + ox) < (unsigned)WW);
            baddr[fn] = v ? (bbase[fn] + disp) : zpk;
        }
        #pragma unroll
        for (int c0 = 0; c0 < 128; c0 += 32) {
            bf16x8 a[4], b[3];
            #pragma unroll
            for (int fm = 0; fm < 4; ++fm)
                a[fm] = *reinterpret_cast<const bf16x8*>(wbase[fm] + t * 128 + c0);
            #pragma unroll
            for (int fn = 0; fn < 3; ++fn)
                b[fn] = *reinterpret_cast<const bf16x8*>(baddr[fn] + c0);
            #pragma unroll
            for (int fm = 0; fm < 4; ++fm)
                #pragma unroll
                for (int fn = 0; fn < 3; ++fn)
                    acc[fm][fn] = __builtin_amdgcn_mfma_f32_16x16x32_bf16(
                        a[fm], b[fn], acc[fm][fn], 0, 0, 0);
        }
    }

    __shared__ float red[2][48][64];
    if (wz) {
        #pragma unroll
        for (int fm = 0; fm < 4; ++fm)
            #pragma unroll
            for (int fn = 0; fn < 3; ++fn)
                #pragma unroll
                for (int r = 0; r < 4; ++r)
                    red[wz - 1][fm * 12 + fn * 4 + r][lane] = acc[fm][fn][r];
    }
    __syncthreads();
    if (wz == 0) {
        #pragma unroll
        for (int fm = 0; fm < 4; ++fm)
            #pragma unroll
            for (int fn = 0; fn < 3; ++fn)
                #pragma unroll
                for (int r = 0; r < 4; ++r)
                    acc[fm][fn][r] += red[0][fm * 12 + fn * 4 + r][lane] +
                                      red[1][fm * 12 + fn * 4 + r][lane];

        #pragma unroll
        for (int fm = 0; fm < 4; ++fm) {
            int o0 = o_base + fm * 16 + kg * 4;
            #pragma unroll
            for (int fn = 0; fn < 3; ++fn) {
                int n = n_base + fn * 16 + l15;
                *reinterpret_cast<f32x4*>(y + (size_t)n * 128 + o0) = acc[fm][fn];
            }
        }

        // BN partials over this block's 48 pixels -> atomic 16-slot accumulators
        float* slot = parts16L + (size_t)(blockIdx.x & 15) * 256;
        #pragma unroll
        for (int fm = 0; fm < 4; ++fm) {
            #pragma unroll
            for (int r = 0; r < 4; ++r) {
                float s = 0.f, s2 = 0.f;
                #pragma unroll
                for (int fn = 0; fn < 3; ++fn) {
                    float v = acc[fm][fn][r];
                    s += v; s2 += v * v;
                }
                #pragma unroll
                for (int m = 1; m <= 8; m <<= 1) {
                    s  += __shfl_xor(s,  m, 64);
                    s2 += __shfl_xor(s2, m, 64);
                }
                if (l15 == 0) {
                    int c = o_base + fm * 16 + kg * 4 + r;
                    unsafeAtomicAdd(slot + c,       s);
                    unsafeAtomicAdd(slot + 128 + c, s2);
                }
            }
        }
    }
}

// ---------------------------------------------------------------------------
// MFMA GEMM for 1x1 convs. Wave tile 64(M) x 16*F(N).  (R8 version)
// MODE 0: bf16 out (+bias); MODE 2: + bf16 residual; MODE 3: f32 scatter+bias.
// ---------------------------------------------------------------------------
template<int WM, int WN, int F, int MODE>
__global__ __launch_bounds__(WM * WN * 64)
void k_gemm(const unsigned short* __restrict__ W,
            const unsigned short* __restrict__ act,
            const float* __restrict__ bias,
            const unsigned short* __restrict__ resid,
            void* __restrict__ outp,
            int Kw, int Cin, int Cout)
{
    int tid = threadIdx.x;
    int lane = tid & 63, wv = tid >> 6;
    int wm = wv % WM, wn = wv / WM;
    int l15 = lane & 15, kg = lane >> 4;

    int n_base = blockIdx.x * (WN * 16 * F) + wn * 16 * F;
    int o_base = blockIdx.y * (WM * 64) + wm * 64;

    const unsigned short* wbase[4];
    #pragma unroll
    for (int fm = 0; fm < 4; ++fm) {
        int o = o_base + fm * 16 + l15;
        wbase[fm] = W + (size_t)o * Kw + kg * 8;
    }

    const unsigned short* bbase[F];
    #pragma unroll
    for (int fn = 0; fn < F; ++fn) {
        int n = n_base + fn * 16 + l15;
        bbase[fn] = act + (size_t)n * Cin + kg * 8;
    }

    f32x4 acc[4][F];
    #pragma unroll
    for (int fm = 0; fm < 4; ++fm)
        #pragma unroll
        for (int fn = 0; fn < F; ++fn)
            acc[fm][fn] = (f32x4){0.f, 0.f, 0.f, 0.f};

    #pragma unroll
    for (int k0 = 0; k0 < 128; k0 += 32) {
        if (k0 >= Cin) break;
        bf16x8 a[4], b[F];
        #pragma unroll
        for (int fm = 0; fm < 4; ++fm)
            a[fm] = *reinterpret_cast<const bf16x8*>(wbase[fm] + k0);
        #pragma unroll
        for (int fn = 0; fn < F; ++fn)
            b[fn] = *reinterpret_cast<const bf16x8*>(bbase[fn] + k0);
        #pragma unroll
        for (int fm = 0; fm < 4; ++fm)
            #pragma unroll
            for (int fn = 0; fn < F; ++fn)
                acc[fm][fn] = __builtin_amdgcn_mfma_f32_16x16x32_bf16(
                    a[fm], b[fn], acc[fm][fn], 0, 0, 0);
    }

    #pragma unroll
    for (int fm = 0; fm < 4; ++fm) {
        #pragma unroll
        for (int fn = 0; fn < F; ++fn) {
            f32x4 v = acc[fm][fn];
            int n = n_base + fn * 16 + l15;
            int o0 = o_base + fm * 16 + kg * 4;
            if constexpr (MODE == 0 || MODE == 2) {
                if (bias) {
                    #pragma unroll
                    for (int r = 0; r < 4; ++r) v[r] += bias[o0 + r];
                }
                if constexpr (MODE == 2) {
                    us4 rv = *reinterpret_cast<const us4*>(resid + (size_t)n * Cout + o0);
                    #pragma unroll
                    for (int r = 0; r < 4; ++r) v[r] += bf2f(rv[r]);
                }
                us4 st;
                #pragma unroll
                for (int r = 0; r < 4; ++r) st[r] = f2bf(v[r]);
                *reinterpret_cast<us4*>((unsigned short*)outp + (size_t)n * Cout + o0) = st;
            } else {
                int b_ = n / PP, p = n - b_ * PP;
                float* op = (float*)outp;
                #pragma unroll
                for (int r = 0; r < 4; ++r)
                    op[((size_t)(b_ * Cout + o0 + r)) * PP + p] = v[r] + bias[o0 + r];
            }
        }
    }
}

// ---------------------------------------------------------------------------
// BN finalize (from 16-slot atomic partials) + apply + ReLU, one kernel.
// Prologue: threads 0..127 reduce parts16L -> scale/shift in LDS.
// Body: y f32 [n][128] -> h bf16 [n][128].
// ---------------------------------------------------------------------------
__global__ __launch_bounds__(256)
void k_bnrelu(const float* __restrict__ y, const float* __restrict__ parts16L,
              const float* __restrict__ g, const float* __restrict__ b,
              unsigned short* __restrict__ h)
{
    __shared__ float scsh[256];
    int tid = threadIdx.x;
    if (tid < 128) {
        float S = 0.f, S2 = 0.f;
        #pragma unroll
        for (int k = 0; k < 16; ++k) {
            S  += parts16L[k * 256 + tid];
            S2 += parts16L[k * 256 + 128 + tid];
        }
        const float inv = 1.f / (float)NN;
        float mu = S * inv;
        float var = S2 * inv - mu * mu;
        float sc = g[tid] * rsqrtf(var + 1e-5f);
        scsh[tid] = sc;
        scsh[128 + tid] = b[tid] - mu * sc;
    }
    __syncthreads();

    int gid = blockIdx.x * 256 + tid;   // quads
    int c0 = (gid * 4) & 127;
    size_t idx = (size_t)gid * 4;
    f32x4 v = *reinterpret_cast<const f32x4*>(y + idx);
    us4 st;
    #pragma unroll
    for (int r = 0; r < 4; ++r) {
        float f = fmaxf(fmaf(v[r], scsh[c0 + r], scsh[128 + c0 + r]), 0.f);
        st[r] = f2bf(f);
    }
    *reinterpret_cast<us4*>(h + idx) = st;
}

// ---------------------------------------------------------------------------
// LDS-staged local channel self-attention (R8 config).
// Block: one image row (96 px) x 2 heads (head-pair hp = blockIdx.y).
// ---------------------------------------------------------------------------
__global__ __launch_bounds__(256)
void k_attn2(const unsigned short* __restrict__ qkv, unsigned short* __restrict__ att)
{
    __shared__ unsigned short tile[288 * 104];   // 59904 B
    int tid = threadIdx.x;
    int br = blockIdx.x;          // 0..191  (b*96 + i)
    int hp = blockIdx.y;          // 0..3    (heads 2hp, 2hp+1)
    int b = br / HH, i = br - (br / HH) * HH;

    #pragma unroll 1
    for (int it = 0; it < 14; ++it) {
        int idx = it * 256 + tid;
        if (idx < 3456) {
            int pp = idx / 12;
            int rem = idx - pp * 12;
            int s = rem >> 2, u8 = rem & 3;
            int rr = pp / 96, col = pp - rr * 96;
            int ai = i + rr - 1;
            us8 val = {0, 0, 0, 0, 0, 0, 0, 0};
            if ((unsigned)ai < (unsigned)HH) {
                int n = b * PP + ai * WW + col;
                val = *reinterpret_cast<const us8*>(
                    qkv + (size_t)n * 384 + s * 128 + hp * 32 + u8 * 8);
            }
            *reinterpret_cast<us8*>(tile + pp * 104 + s * 32 + u8 * 8) = val;
        }
    }
    __syncthreads();

    #pragma unroll 1
    for (int u = 0; u < 3; ++u) {
        int unit = u * 256 + tid;   // 0..767
        int j  = unit >> 3;
        int h  = (unit >> 2) & 1;
        int ng = unit & 3;

        float dots[4][16];
        float vs[16];
        #pragma unroll
        for (int m = 0; m < 16; ++m) vs[m] = 0.f;
        #pragma unroll
        for (int nn = 0; nn < 4; ++nn)
            #pragma unroll
            for (int m = 0; m < 16; ++m) dots[nn][m] = 0.f;

        #pragma unroll 1
        for (int rr = 0; rr < 3; ++rr) {
            #pragma unroll
            for (int dj = -1; dj <= 1; ++dj) {
                int jj = j + dj;
                if ((unsigned)jj >= (unsigned)WW) continue;
                const unsigned short* pb = tile + (rr * 96 + jj) * 104 + h * 16;
                us4 q4 = *reinterpret_cast<const us4*>(pb + ng * 4);
                us8 k0 = *reinterpret_cast<const us8*>(pb + 32);
                us8 k1 = *reinterpret_cast<const us8*>(pb + 40);
                us8 v0 = *reinterpret_cast<const us8*>(pb + 64);
                us8 v1 = *reinterpret_cast<const us8*>(pb + 72);
                float kf[16];
                #pragma unroll
                for (int e = 0; e < 8; ++e) {
                    kf[e] = bf2f(k0[e]);
                    kf[8 + e] = bf2f(k1[e]);
                    vs[e] += bf2f(v0[e]);
                    vs[8 + e] += bf2f(v1[e]);
                }
                #pragma unroll
                for (int nn = 0; nn < 4; ++nn) {
                    float qf = bf2f(q4[nn]);
                    #pragma unroll
                    for (int m = 0; m < 16; ++m)
                        dots[nn][m] = fmaf(qf, kf[m], dots[nn][m]);
                }
            }
        }

        us4 st;
        #pragma unroll
        for (int nn = 0; nn < 4; ++nn) {
            float mx = dots[nn][0];
            #pragma unroll
            for (int m = 1; m < 16; ++m) mx = fmaxf(mx, dots[nn][m]);
            float den = 0.f, o = 0.f;
            #pragma unroll
            for (int m = 0; m < 16; ++m) {
                float e = __expf(dots[nn][m] - mx);
                den += e;
                o = fmaf(e, vs[m], o);
            }
            st[nn] = f2bf(o / den);
        }
        int n = b * PP + i * WW + j;
        *reinterpret_cast<us4*>(att + (size_t)n * CC + hp * 32 + h * 16 + ng * 4) = st;
    }
}

// ---------------------------------------------------------------------------
extern "C" void kernel_launch(void* const* d_in, const int* in_sizes, int n_in,
                              void* d_out, int out_size, void* d_ws, size_t ws_size,
                              hipStream_t stream)
{
    const float* x      = (const float*)d_in[0];
    const float* w_in   = (const float*)d_in[1];
    const float* b_in   = (const float*)d_in[2];
    const float* conv_w = (const float*)d_in[3];
    const float* bn_g   = (const float*)d_in[5];
    const float* bn_b   = (const float*)d_in[6];
    const float* qkv_w  = (const float*)d_in[7];
    const float* fc_w   = (const float*)d_in[8];
    const float* fc_b   = (const float*)d_in[9];
    const float* w_out  = (const float*)d_in[10];
    const float* b_out  = (const float*)d_in[11];

    char* ws = (char*)d_ws;
    unsigned short* zp     = (unsigned short*)(ws);              // 4096 B zeros
    float*          parts16= (float*)        (ws + 4096);        // 4*16*256*4 = 65536 B
    unsigned short* wcv    = (unsigned short*)(ws + 69632);      // 1,179,648
    unsigned short* wqkv   = (unsigned short*)(ws + 1249280);    //   393,216
    unsigned short* wfc    = (unsigned short*)(ws + 1642496);    //   131,072
    unsigned short* wi     = (unsigned short*)(ws + 1773568);    //    16,384
    unsigned short* wo     = (unsigned short*)(ws + 1789952);    //    16,384
    unsigned short* xT     = (unsigned short*)(ws + 1806336);    // 2,359,296
    unsigned short* bufA   = (unsigned short*)(ws + 4165632);    // 4,718,592
    float*          ybuf   = (float*)        (ws + 8884224);     // 9,437,184
    unsigned short* hbuf   = (unsigned short*)(ws + 18321408);   // 4,718,592
    unsigned short* qkvb   = (unsigned short*)(ws + 23040000);   // 14,155,776
    unsigned short* attb   = (unsigned short*)(ws + 37195776);   // 4,718,592

    // zero pad page + all 4 layers' atomic BN partials in one memset
    hipMemsetAsync(ws, 0, 69632, stream);

    k_wconv<<<3464, 256, 0, stream>>>(conv_w, qkv_w, fc_w, w_in, w_out, x,
                                      wcv, wqkv, wfc, wi, wo, xT);

    // in-proj: 64 -> 128, bias -> bufA (bf16)
    k_gemm<1, 2, 3, 0><<<dim3(192, 2), 128, 0, stream>>>(
        wi, xT, b_in, nullptr, bufA, 64, 64, 128);

    for (int L = 0; L < 4; ++L) {
        const unsigned short* wc = wcv + (size_t)L * 147456;
        float* pL = parts16 + (size_t)L * 4096;
        switch (L) {
            case 0: k_conv<1><<<dim3(CONV_BLKS, 2), 192, 0, stream>>>(wc, bufA, ybuf, pL, zp); break;
            case 1: k_conv<2><<<dim3(CONV_BLKS, 2), 192, 0, stream>>>(wc, bufA, ybuf, pL, zp); break;
            case 2: k_conv<4><<<dim3(CONV_BLKS, 2), 192, 0, stream>>>(wc, bufA, ybuf, pL, zp); break;
            case 3: k_conv<8><<<dim3(CONV_BLKS, 2), 192, 0, stream>>>(wc, bufA, ybuf, pL, zp); break;
        }
        // BN finalize (from atomic partials) + apply + ReLU -> hbuf
        k_bnrelu<<<2304, 256, 0, stream>>>(ybuf, pL, bn_g + L * 128, bn_b + L * 128, hbuf);

        // qkv: 128 -> 384 -> qkvb
        k_gemm<1, 2, 3, 0><<<dim3(192, 6), 128, 0, stream>>>(
            wqkv + (size_t)L * 49152, hbuf, nullptr, nullptr, qkvb, 128, 128, 384);

        // LDS-staged attention (head pairs) -> attb
        k_attn2<<<dim3(BB * HH, 4), 256, 0, stream>>>(qkvb, attb);

        // fc: 128 -> 128 + bias + residual(hbuf) -> bufA
        k_gemm<1, 2, 3, 2><<<dim3(192, 2), 128, 0, stream>>>(
            wfc + (size_t)L * 16384, attb, fc_b + L * 128, hbuf, bufA, 128, 128, 128);
    }

    // out-proj: 128 -> 64, bias, f32 scatter to d_out
    k_gemm<1, 2, 3, 3><<<dim3(192, 1), 128, 0, stream>>>(
        wo, bufA, b_out, nullptr, (float*)d_out, 128, 128, 64);
}